// Round 2
// baseline (101.039 us; speedup 1.0000x reference)
//
#include <hip/hip_runtime.h>
#include <stdint.h>

// Problem constants (match reference)
#define Bdim 64
#define Tdim 1024
#define Edim 128
#define Cdim 5
#define Fdim 64
#define Hpad 2      // C/2
#define Kdim (Cdim * Edim)   // 640

// Tile geometry (TTILE=64 measured sweet spot: 32->90.1, 64->87.8, 128->97.4)
#define TTILE 64                 // t-positions per workgroup
#define XROWS (TTILE + Cdim - 1) // 68 rows: t0-2 .. t0+65
#define LDSTR (Edim + 8)         // 136 shorts/row

typedef __attribute__((ext_vector_type(8))) short short8;     // 8 bf16 = 4 VGPRs (MFMA frag)
typedef __attribute__((ext_vector_type(4))) float float4v;
typedef __attribute__((ext_vector_type(4))) unsigned short ushort4v;

__device__ __forceinline__ unsigned short f2bf(float f) {
    // round-to-nearest-even fp32 -> bf16 (inputs finite randn; no NaN path needed)
    union { float f; uint32_t u; } v; v.f = f;
    uint32_t u = v.u;
    u += 0x7fffu + ((u >> 16) & 1u);
    return (unsigned short)(u >> 16);
}

// ---- Pre-kernel: W fp32 [F, C*E] -> bf16, swizzled into MFMA B-fragment order:
//   Wbf[(((c*4 + kk)*4 + wave)*4 + quad)*128 + m16*8 + j]
// where f = wave*16 + m16, k = c*128 + kk*32 + quad*8 + j.
// A wave's per-(c,kk) fragment load is 1 KB fully contiguous (16 B/lane).
// R1 lesson: replacing this with per-lane gathers from fp32 W (2560 B lane
// stride) + the extra VGPR pressure cost ~9-13us. Workspace poison is
// unconditional, so the ws-based swizzle is free. Keep it.
__global__ void convert_W(const float* __restrict__ W, unsigned short* __restrict__ Wbf) {
    int i = blockIdx.x * 256 + threadIdx.x;      // float4 slot, 10240 total
    if (i >= (Fdim * Kdim) / 4) return;
    const int e0 = i * 4;                        // flat input index, 4-aligned
    const int f  = e0 / Kdim;
    const int k  = e0 % Kdim;
    const int c    = k / Edim;
    const int kin  = k % Edim;
    const int kk   = kin / 32;
    const int q8   = kin % 32;
    const int quad = q8 / 8;
    const int j0   = q8 % 8;                     // 0 or 4
    float4v v = ((const float4v*)W)[i];
    ushort4v o = { f2bf(v.x), f2bf(v.y), f2bf(v.z), f2bf(v.w) };
    const int dst = (((c * 4 + kk) * 4 + (f >> 4)) * 4 + quad) * 128 + (f & 15) * 8 + j0;
    *(ushort4v*)&Wbf[dst] = o;
}

// ---- Main kernel: one block = 64 t-positions of one batch row; 4 waves split F.
// Single barrier. Batched staging loads (R1 ingredient: issue all 9 global
// loads before converting -> MLP hides HBM latency). B-fragments pipelined
// one tap ahead from swizzled Wbf (L2-hot, 80 KB, contiguous 1 KB/wave).
__global__ __launch_bounds__(256, 4)
void qa_cnn_main(const float* __restrict__ x, const unsigned short* __restrict__ Wbf,
                 const float* __restrict__ bias, float* __restrict__ out) {
    __shared__ __align__(16) unsigned short sX[XROWS * LDSTR]; // 18,496 B

    const int tid = threadIdx.x;
    const int tt  = blockIdx.x;   // 0..15
    const int b   = blockIdx.y;   // 0..63
    const int t0  = tt * TTILE;

    const int wave = tid >> 6;     // 0..3 -> this wave's 16-f slice
    const int lane = tid & 63;
    const int m16  = lane & 15;
    const int quad = lane >> 4;

    // Swizzled fragment base: per (c,kk) stride = 4 waves * 4 quads * 128 = 2048 shorts.
    const unsigned short* wfrag = Wbf + wave * 512 + quad * 128 + m16 * 8;

    // ---- Stage x window: issue ALL 9 global loads first, then convert+store.
    // i<8 covers idx 0..2047 unconditionally; i==8 partial (tid<128).
    float4v xv[9];
    #pragma unroll
    for (int i = 0; i < 8; ++i) {
        const int idx = tid + i * 256;
        const int row = idx >> 5;
        const int c4  = idx & 31;
        const int gt  = t0 - Hpad + row;
        float4v v = {0.f, 0.f, 0.f, 0.f};
        if (gt >= 0 && gt < Tdim)
            v = *(const float4v*)(x + ((size_t)b * Tdim + gt) * Edim + c4 * 4);
        xv[i] = v;
    }
    {
        const int idx = tid + 2048;
        float4v v = {0.f, 0.f, 0.f, 0.f};
        if (idx < XROWS * (Edim / 4)) {
            const int row = idx >> 5;
            const int c4  = idx & 31;
            const int gt  = t0 - Hpad + row;
            if (gt >= 0 && gt < Tdim)
                v = *(const float4v*)(x + ((size_t)b * Tdim + gt) * Edim + c4 * 4);
        }
        xv[8] = v;
    }

    // Prefetch tap-0 B-fragments (bf16, contiguous) while x loads are in flight.
    short8 bcur[4];
    #pragma unroll
    for (int kk = 0; kk < 4; ++kk)
        bcur[kk] = *(const short8*)(wfrag + kk * 2048);

    #pragma unroll
    for (int i = 0; i < 8; ++i) {
        const int idx = tid + i * 256;
        const int row = idx >> 5;
        const int c4  = idx & 31;
        ushort4v o = { f2bf(xv[i].x), f2bf(xv[i].y), f2bf(xv[i].z), f2bf(xv[i].w) };
        *(ushort4v*)&sX[row * LDSTR + c4 * 4] = o;
    }
    if (tid < 128) {
        const int idx = tid + 2048;
        const int row = idx >> 5;
        const int c4  = idx & 31;
        ushort4v o = { f2bf(xv[8].x), f2bf(xv[8].y), f2bf(xv[8].z), f2bf(xv[8].w) };
        *(ushort4v*)&sX[row * LDSTR + c4 * 4] = o;
    }

    float4v acc[4];
    #pragma unroll
    for (int mt = 0; mt < 4; ++mt) acc[mt] = (float4v){0.f, 0.f, 0.f, 0.f};

    __syncthreads();   // the only barrier

    #pragma unroll
    for (int c = 0; c < Cdim; ++c) {
        // Pipeline: fetch next tap's B-fragments before this tap's MFMAs.
        short8 bnxt[4];
        if (c + 1 < Cdim) {
            #pragma unroll
            for (int kk = 0; kk < 4; ++kk)
                bnxt[kk] = *(const short8*)(wfrag + ((c + 1) * 4 + kk) * 2048);
        }

        #pragma unroll
        for (int kk = 0; kk < 4; ++kk) {
            const int kcol = kk * 32 + quad * 8;
            #pragma unroll
            for (int mt = 0; mt < 4; ++mt) {
                // A[m = m16][k], row in sX shifted by tap c
                const short8 a = *(const short8*)&sX[(c + mt * 16 + m16) * LDSTR + kcol];
                acc[mt] = __builtin_amdgcn_mfma_f32_16x16x32_bf16(a, bcur[kk], acc[mt], 0, 0, 0);
            }
        }

        if (c + 1 < Cdim) {
            #pragma unroll
            for (int kk = 0; kk < 4; ++kk) bcur[kk] = bnxt[kk];
        }
    }

    // Epilogue: D col(n)=lane&15 -> f, row(m)=quad*4+reg -> t. 4 consecutive t/lane.
    // The 4 mt stores per lane-group fill a full 256 B f-row segment between
    // them, so L2 write-combining sees whole 128 B lines; no transpose needed.
    const int f  = wave * 16 + m16;
    const float bv = bias[f];
    float* orow = out + ((size_t)b * Fdim + f) * Tdim + t0 + quad * 4;
    #pragma unroll
    for (int mt = 0; mt < 4; ++mt) {
        float4v v = acc[mt];
        v.x += bv; v.y += bv; v.z += bv; v.w += bv;
        *(float4v*)(orow + mt * 16) = v;
    }
}

extern "C" void kernel_launch(void* const* d_in, const int* in_sizes, int n_in,
                              void* d_out, int out_size, void* d_ws, size_t ws_size,
                              hipStream_t stream) {
    (void)in_sizes; (void)n_in; (void)out_size; (void)ws_size;
    const float* x    = (const float*)d_in[0];   // [B, T, E]
    const float* W    = (const float*)d_in[1];   // [F, C*E]
    const float* bias = (const float*)d_in[2];   // [F]
    float* out = (float*)d_out;                  // [B, F, T]
    unsigned short* Wbf = (unsigned short*)d_ws; // 80 KB swizzled bf16 copy of W

    convert_W<<<dim3((Fdim * Kdim / 4 + 255) / 256), dim3(256), 0, stream>>>(W, Wbf);
    qa_cnn_main<<<dim3(Tdim / TTILE, Bdim), dim3(256), 0, stream>>>(x, Wbf, bias, out);
    // R2 CALIBRATION: second identical launch (idempotent — writes the same
    // bits). main_dur = dur_R2 - dur_R0(88.7). This pins how much of the
    // timed region is actually our kernel vs unconditional harness poison,
    // which decides whether further structural optimization can pay at all.
    qa_cnn_main<<<dim3(Tdim / TTILE, Bdim), dim3(256), 0, stream>>>(x, Wbf, bias, out);
}

// Round 3
// 88.390 us; speedup vs baseline: 1.1431x; 1.1431x over previous
//
#include <hip/hip_runtime.h>
#include <stdint.h>

// Problem constants (match reference)
#define Bdim 64
#define Tdim 1024
#define Edim 128
#define Cdim 5
#define Fdim 64
#define Hpad 2      // C/2
#define Kdim (Cdim * Edim)   // 640

// Tile geometry. TTILE=64 sweet spot (32->90.1, 64->87.8, 128->97.4 in prior
// session). R3: each block now pipelines TWO adjacent tiles (t0, t0+64) with
// double-buffered LDS, 512 blocks = 2/CU.
#define TTILE 64                 // t-positions per tile
#define XROWS (TTILE + Cdim - 1) // 68 rows: t0-2 .. t0+65
#define LDSTR (Edim + 8)         // 136 shorts/row
#define NSLOT (XROWS * (Edim / 4)) // 2176 float4 slots per tile stage

typedef __attribute__((ext_vector_type(8))) short short8;     // 8 bf16 = 4 VGPRs (MFMA frag)
typedef __attribute__((ext_vector_type(4))) float float4v;
typedef __attribute__((ext_vector_type(4))) unsigned short ushort4v;

__device__ __forceinline__ unsigned short f2bf(float f) {
    // round-to-nearest-even fp32 -> bf16 (inputs finite randn; no NaN path needed)
    union { float f; uint32_t u; } v; v.f = f;
    uint32_t u = v.u;
    u += 0x7fffu + ((u >> 16) & 1u);
    return (unsigned short)(u >> 16);
}

// ---- Pre-kernel: W fp32 [F, C*E] -> bf16, swizzled into MFMA B-fragment order:
//   Wbf[(((c*4 + kk)*4 + wave)*4 + quad)*128 + m16*8 + j]
// where f = wave*16 + m16, k = c*128 + kk*32 + quad*8 + j.
// A wave's per-(c,kk) fragment load is 1 KB fully contiguous (16 B/lane).
// R1 lesson: in-main fp32 gathers + register pressure cost ~13us; ws poison is
// unconditional so this 80 KB ws staging is free. Keep it.
__global__ void convert_W(const float* __restrict__ W, unsigned short* __restrict__ Wbf) {
    int i = blockIdx.x * 256 + threadIdx.x;      // float4 slot, 10240 total
    if (i >= (Fdim * Kdim) / 4) return;
    const int e0 = i * 4;                        // flat input index, 4-aligned
    const int f  = e0 / Kdim;
    const int k  = e0 % Kdim;
    const int c    = k / Edim;
    const int kin  = k % Edim;
    const int kk   = kin / 32;
    const int q8   = kin % 32;
    const int quad = q8 / 8;
    const int j0   = q8 % 8;                     // 0 or 4
    float4v v = ((const float4v*)W)[i];
    ushort4v o = { f2bf(v.x), f2bf(v.y), f2bf(v.z), f2bf(v.w) };
    const int dst = (((c * 4 + kk) * 4 + (f >> 4)) * 4 + quad) * 128 + (f & 15) * 8 + j0;
    *(ushort4v*)&Wbf[dst] = o;
}

// ---- Main kernel (R3): one block = 128 t-positions (two 64-t tiles, double-
// buffered LDS) of one batch row; 4 waves split F. R2 calibration: main ~12.3us
// vs ~8.3us BW floor -> the gap is one-shot phase serialization. Pipeline:
//   stage(T0) | bar | loads(T1) + MFMA(T0) + write(T1) + store(T0) | bar | MFMA(T1) + store(T1)
// All 20 B-fragments (tile-invariant, 80 VGPR) hoisted; __launch_bounds__(256,2)
// lifts the VGPR cap (grid = exactly 2 blocks/CU regardless).
__global__ __launch_bounds__(256, 2)
void qa_cnn_main(const float* __restrict__ x, const unsigned short* __restrict__ Wbf,
                 const float* __restrict__ bias, float* __restrict__ out) {
    __shared__ __align__(16) unsigned short sX[2][XROWS * LDSTR]; // 2 x 18,496 B

    const int tid = threadIdx.x;
    const int blk = blockIdx.x;   // 0..7
    const int b   = blockIdx.y;   // 0..63
    const int t0  = blk * (2 * TTILE);

    const int wave = tid >> 6;     // 0..3 -> this wave's 16-f slice
    const int lane = tid & 63;
    const int m16  = lane & 15;
    const int quad = lane >> 4;

    // Swizzled fragment base: per (c,kk) stride = 4 waves * 4 quads * 128 = 2048 shorts.
    const unsigned short* wfrag = Wbf + wave * 512 + quad * 128 + m16 * 8;

    // Batched issue of one tile's 9 x-loads (MLP across the wave hides HBM latency).
    auto issue_loads = [&](int t0loc, float4v xv[9]) {
        #pragma unroll
        for (int i = 0; i < 9; ++i) {
            const int idx = tid + i * 256;
            float4v v = {0.f, 0.f, 0.f, 0.f};
            if (idx < NSLOT) {                       // i<8 folds to true
                const int row = idx >> 5;
                const int c4  = idx & 31;
                const int gt  = t0loc - Hpad + row;
                if (gt >= 0 && gt < Tdim)
                    v = *(const float4v*)(x + ((size_t)b * Tdim + gt) * Edim + c4 * 4);
            }
            xv[i] = v;
        }
    };
    auto write_lds = [&](unsigned short* dst, const float4v xv[9]) {
        #pragma unroll
        for (int i = 0; i < 9; ++i) {
            const int idx = tid + i * 256;
            if (idx < NSLOT) {
                const int row = idx >> 5;
                const int c4  = idx & 31;
                ushort4v o = { f2bf(xv[i].x), f2bf(xv[i].y), f2bf(xv[i].z), f2bf(xv[i].w) };
                *(ushort4v*)&dst[row * LDSTR + c4 * 4] = o;
            }
        }
    };

    // ---- Stage tile 0; W fragments (L2-hot) load in the same shadow.
    float4v xv[9];
    issue_loads(t0, xv);

    short8 bfr[20];                  // all (c,kk) B-fragments, tile-invariant
    #pragma unroll
    for (int ck = 0; ck < 20; ++ck)
        bfr[ck] = *(const short8*)(wfrag + ck * 2048);

    write_lds(sX[0], xv);

    auto compute = [&](const unsigned short* sbuf, float4v acc[4]) {
        #pragma unroll
        for (int c = 0; c < Cdim; ++c) {
            #pragma unroll
            for (int kk = 0; kk < 4; ++kk) {
                const int kcol = kk * 32 + quad * 8;
                #pragma unroll
                for (int mt = 0; mt < 4; ++mt) {
                    // A[m = m16][k], row shifted by tap c
                    const short8 a = *(const short8*)&sbuf[(c + mt * 16 + m16) * LDSTR + kcol];
                    acc[mt] = __builtin_amdgcn_mfma_f32_16x16x32_bf16(a, bfr[c * 4 + kk], acc[mt], 0, 0, 0);
                }
            }
        }
    };

    const int f  = wave * 16 + m16;
    const float bv = bias[f];
    auto store_out = [&](const float4v acc[4], int t0loc) {
        // D col(n)=lane&15 -> f, row(m)=quad*4+reg -> t. 4 consecutive t/lane.
        float* orow = out + ((size_t)b * Fdim + f) * Tdim + t0loc + quad * 4;
        #pragma unroll
        for (int mt = 0; mt < 4; ++mt) {
            float4v v = acc[mt];
            v.x += bv; v.y += bv; v.z += bv; v.w += bv;
            *(float4v*)(orow + mt * 16) = v;
        }
    };

    __syncthreads();   // tile-0 buffer ready

    // ---- Pipelined iteration: tile-1 HBM reads hide under tile-0 compute+store.
    issue_loads(t0 + TTILE, xv);     // issued first -> in flight during MFMAs

    float4v acc[4];
    #pragma unroll
    for (int mt = 0; mt < 4; ++mt) acc[mt] = (float4v){0.f, 0.f, 0.f, 0.f};
    compute(sX[0], acc);

    write_lds(sX[1], xv);            // waits vmcnt here, after compute
    store_out(acc, t0);              // tile-0 writes overlap tile-1 stage tail

    __syncthreads();   // tile-1 buffer ready

    #pragma unroll
    for (int mt = 0; mt < 4; ++mt) acc[mt] = (float4v){0.f, 0.f, 0.f, 0.f};
    compute(sX[1], acc);
    store_out(acc, t0 + TTILE);
}

extern "C" void kernel_launch(void* const* d_in, const int* in_sizes, int n_in,
                              void* d_out, int out_size, void* d_ws, size_t ws_size,
                              hipStream_t stream) {
    (void)in_sizes; (void)n_in; (void)out_size; (void)ws_size;
    const float* x    = (const float*)d_in[0];   // [B, T, E]
    const float* W    = (const float*)d_in[1];   // [F, C*E]
    const float* bias = (const float*)d_in[2];   // [F]
    float* out = (float*)d_out;                  // [B, F, T]
    unsigned short* Wbf = (unsigned short*)d_ws; // 80 KB swizzled bf16 copy of W

    convert_W<<<dim3((Fdim * Kdim / 4 + 255) / 256), dim3(256), 0, stream>>>(W, Wbf);
    qa_cnn_main<<<dim3(Tdim / (2 * TTILE), Bdim), dim3(256), 0, stream>>>(x, Wbf, bias, out);
}